// Round 1
// baseline (5617.730 us; speedup 1.0000x reference)
//
#include <hip/hip_runtime.h>
#include <math.h>

// Geometry constants (all axes symmetric: 128 cells, 400mm, centered at 0)
constexpr float DXC    = 400.0f / 128.0f;                    // 3.125
constexpr float XMINC  = -200.0f;
constexpr float KW2    = 9.0f * 3.14159265358979323846f;     // KERNEL_WIDTH^2 = 9*pi
constexpr float INV2S2 = 2.0f / KW2;                         // 1/(2*sigma^2) = 2/KW^2

// AXIS 0 (xlors, perm [1,2,0]): val = image[k][ii][jj]  -> SI=128,   SJ=1,   SK=16384
// AXIS 1 (ylors, perm [0,2,1]): val = image[ii][k][jj]  -> SI=16384, SJ=1,   SK=128
// AXIS 2 (zlors, perm [0,1,2]): val = image[ii][jj][k]  -> SI=16384, SJ=128, SK=1
template <int AXIS>
__global__ __launch_bounds__(256) void proj_kernel(const float* __restrict__ img,
                                                   const float* __restrict__ lors,
                                                   float* __restrict__ out, int n)
{
    int id = blockIdx.x * blockDim.x + threadIdx.x;
    if (id >= n) return;

    const float* l = lors + (size_t)id * 6;
    float l0 = l[0], l1 = l[1], l2 = l[2], l3 = l[3], l4 = l[4], l5 = l[5];

    float p0x, p0y, p0z, p1x, p1y, p1z;
    if (AXIS == 0)      { p0x = l1; p0y = l2; p0z = l0; p1x = l4; p1y = l5; p1z = l3; }
    else if (AXIS == 1) { p0x = l0; p0y = l2; p0z = l1; p1x = l3; p1y = l5; p1z = l4; }
    else                { p0x = l0; p0y = l1; p0z = l2; p1x = l3; p1y = l4; p1z = l5; }

    float dvx = p1x - p0x, dvy = p1y - p0y, dvz = p1z - p0z;
    float L    = sqrtf(dvx * dvx + dvy * dvy + dvz * dvz);
    float path = DXC * L / fabsf(dvz);
    float invdz = 1.0f / dvz;

    constexpr int SI = (AXIS == 0) ? 128 : 16384;
    constexpr int SJ = (AXIS == 2) ? 128 : 1;
    constexpr int SK = (AXIS == 0) ? 16384 : ((AXIS == 1) ? 128 : 1);

    float acc = 0.0f;

    for (int k = 0; k < 128; ++k) {
        float zc = XMINC + ((float)k + 0.5f) * DXC;
        float t  = (zc - p0z) * invdz;
        if (t < 0.0f || t > 1.0f) continue;

        float xc = p0x + t * dvx;
        float yc = p0y + t * dvy;
        float u  = (xc - XMINC) * (1.0f / DXC);
        float v  = (yc - XMINC) * (1.0f / DXC);
        float fi0 = floorf(u), fj0 = floorf(v);
        int   i0 = (int)fi0, j0 = (int)fj0;
        float fu = u - fi0, fv = v - fj0;

        float a[5], b[5], ea[5], eb[5];
        int   ic[5], jc[5];
#pragma unroll
        for (int d = 0; d < 5; ++d) {
            float dxp = ((float)(d - 2) + 0.5f - fu) * DXC;
            float dyp = ((float)(d - 2) + 0.5f - fv) * DXC;
            a[d] = dxp * dxp;
            b[d] = dyp * dyp;
            int ii = i0 + d - 2;
            int jj = j0 + d - 2;
            ea[d] = (ii >= 0 && ii < 128) ? __expf(-a[d] * INV2S2) : 0.0f;
            eb[d] = (jj >= 0 && jj < 128) ? __expf(-b[d] * INV2S2) : 0.0f;
            ic[d] = min(max(ii, 0), 127) * SI;
            jc[d] = min(max(jj, 0), 127) * SJ;
        }

        const float* base = img + (size_t)k * SK;
        float ssum = 0.0f;
#pragma unroll
        for (int di = 0; di < 5; ++di) {
            const float* row = base + ic[di];
            float eai = ea[di], ai = a[di];
#pragma unroll
            for (int dj = 0; dj < 5; ++dj) {
                float d2 = ai + b[dj];
                float w  = eai * eb[dj];
                w = (d2 <= KW2) ? w : 0.0f;
                ssum = fmaf(w, row[jc[dj]], ssum);
            }
        }
        acc += ssum;
    }

    out[(size_t)AXIS * n + id] = acc * path;
}

extern "C" void kernel_launch(void* const* d_in, const int* in_sizes, int n_in,
                              void* d_out, int out_size, void* d_ws, size_t ws_size,
                              hipStream_t stream) {
    const float* img   = (const float*)d_in[0];
    const float* xlors = (const float*)d_in[1];
    const float* ylors = (const float*)d_in[2];
    const float* zlors = (const float*)d_in[3];
    float* out = (float*)d_out;

    int n = in_sizes[1] / 6;
    dim3 block(256);
    dim3 grid((n + 255) / 256);

    proj_kernel<0><<<grid, block, 0, stream>>>(img, xlors, out, n);
    proj_kernel<1><<<grid, block, 0, stream>>>(img, ylors, out, n);
    proj_kernel<2><<<grid, block, 0, stream>>>(img, zlors, out, n);
}

// Round 2
// 1945.418 us; speedup vs baseline: 2.8877x; 2.8877x over previous
//
#include <hip/hip_runtime.h>
#include <math.h>

// Geometry: 128^3 grid, 400mm cube, centered. All axes symmetric.
constexpr float DXC    = 400.0f / 128.0f;                    // 3.125 mm
constexpr float INV_DX = 128.0f / 400.0f;
constexpr float XMINC  = -200.0f;
constexpr float KW2    = 9.0f * 3.14159265358979323846f;     // cutoff^2 = 9*pi (mm^2)
constexpr float INV2S2 = 2.0f / KW2;                         // 1/(2 sigma^2)
constexpr float NEGL2  = -INV2S2 * 1.4426950408889634f;      // for exp2f
// Support radius = KW/DXC = 1.7016 cells -> 4 rows x 4 cols always suffice.
// Margin constant M = R - 0.5 (+eps):
constexpr float MARG   = 1.2017f;

constexpr int CHUNKS = 8;            // k-chunks per LOR
constexpr int KCH    = 128 / CHUNKS; // 16 slices per thread

// Layouts (img[k][i][j]-style strides after permutation):
// AXIS 0 (xlors): val = image[k][ii][jj]   -> SI=128,   SJ=1,   SK=16384
// AXIS 1 (ylors): val = image[ii][k][jj]   -> SI=16384, SJ=1,   SK=128
// AXIS 2 (zlors): val = image[ii][jj][k]   -> SI=16384, SJ=128, SK=1   (scalar fallback)
//        with transpose T2[k][i][j]        -> SI=128,   SJ=1,   SK=16384 (vector path)
template <int AXIS, bool VEC>
__global__ __launch_bounds__(256) void proj_kernel(const float* __restrict__ img,
                                                   const float* __restrict__ lors,
                                                   float* __restrict__ out, int n)
{
    int gid = blockIdx.x * blockDim.x + threadIdx.x;
    int lor = gid >> 3;
    int c   = gid & 7;
    if (lor >= n) return;

    const float* l = lors + (size_t)lor * 6;
    float l0 = l[0], l1 = l[1], l2 = l[2], l3 = l[3], l4 = l[4], l5 = l[5];

    float p0x, p0y, p0z, p1x, p1y, p1z;
    if (AXIS == 0)      { p0x = l1; p0y = l2; p0z = l0; p1x = l4; p1y = l5; p1z = l3; }
    else if (AXIS == 1) { p0x = l0; p0y = l2; p0z = l1; p1x = l3; p1y = l5; p1z = l4; }
    else                { p0x = l0; p0y = l1; p0z = l2; p1x = l3; p1y = l4; p1z = l5; }

    float dvx = p1x - p0x, dvy = p1y - p0y, dvz = p1z - p0z;
    float L     = sqrtf(dvx * dvx + dvy * dvy + dvz * dvz);
    float path  = DXC * L / fabsf(dvz);
    float invdz = 1.0f / dvz;

    constexpr int SI = (AXIS == 1 || (AXIS == 2 && !VEC)) ? 16384 : 128;
    constexpr int SK = (AXIS == 1) ? 128 : ((AXIS == 2 && !VEC) ? 1 : 16384);
    constexpr int SJ = (AXIS == 2 && !VEC) ? 128 : 1;

    float acc = 0.0f;

    for (int k = c * KCH; k < c * KCH + KCH; ++k) {
        float zc = XMINC + ((float)k + 0.5f) * DXC;
        float t  = (zc - p0z) * invdz;
        if (t < 0.0f || t > 1.0f) continue;

        float xc = p0x + t * dvx;
        float yc = p0y + t * dvy;
        float u  = (xc - XMINC) * INV_DX;   // cell coordinates
        float v  = (yc - XMINC) * INV_DX;

        // 4-row / 4-col true support window (anchor from top; cutoff zeroes extras)
        int is  = (int)floorf(u + MARG) - 3;
        int jsn = (int)floorf(v + MARG) - 3;

        const float* imgk = img + (size_t)k * SK;

        float ea[4], ar[4];
        const float* rowp[4];
#pragma unroll
        for (int r = 0; r < 4; ++r) {
            int ii = is + r;
            float dxp = ((float)ii + 0.5f - u) * DXC;
            float a = dxp * dxp;
            float e = exp2f(a * NEGL2);
            ea[r] = (ii >= 0 && ii < 128 && a <= KW2) ? e : 0.0f;
            ar[r] = a;
            rowp[r] = imgk + min(max(ii, 0), 127) * SI;
        }

        float ssum = 0.0f;
        if (VEC) {
            // 8 aligned columns via 2x float4 per row; cutoff gate zeroes extras.
            int js = min(max(jsn & ~3, 0), 120);
            float eb[8], br[8];
#pragma unroll
            for (int m = 0; m < 8; ++m) {
                float dyp = ((float)(js + m) + 0.5f - v) * DXC;
                float b = dyp * dyp;
                float e = exp2f(b * NEGL2);
                eb[m] = (b <= KW2) ? e : 0.0f;
                br[m] = b;
            }
#pragma unroll
            for (int r = 0; r < 4; ++r) {
                const float* p = rowp[r] + js;
                float4 q0 = *reinterpret_cast<const float4*>(p);
                float4 q1 = *reinterpret_cast<const float4*>(p + 4);
                float vals[8] = {q0.x, q0.y, q0.z, q0.w, q1.x, q1.y, q1.z, q1.w};
                float eai = ea[r], ai = ar[r];
#pragma unroll
                for (int m = 0; m < 8; ++m) {
                    float w = (ai + br[m] <= KW2) ? eai * eb[m] : 0.0f;
                    ssum = fmaf(w, vals[m], ssum);
                }
            }
        } else {
            // scalar-gather path (axis 2 without transpose): 4x4 support
            float eb[4]; int jco[4]; float br[4];
#pragma unroll
            for (int m = 0; m < 4; ++m) {
                int jj = jsn + m;
                float dyp = ((float)jj + 0.5f - v) * DXC;
                float b = dyp * dyp;
                float e = exp2f(b * NEGL2);
                eb[m] = (jj >= 0 && jj < 128 && b <= KW2) ? e : 0.0f;
                br[m] = b;
                jco[m] = min(max(jj, 0), 127) * SJ;
            }
#pragma unroll
            for (int r = 0; r < 4; ++r) {
                float eai = ea[r], ai = ar[r];
#pragma unroll
                for (int m = 0; m < 4; ++m) {
                    float w = (ai + br[m] <= KW2) ? eai * eb[m] : 0.0f;
                    ssum = fmaf(w, rowp[r][jco[m]], ssum);
                }
            }
        }
        acc += ssum;
    }

    float val = acc * path;
    val += __shfl_xor(val, 1);
    val += __shfl_xor(val, 2);
    val += __shfl_xor(val, 4);
    if (c == 0) out[(size_t)AXIS * n + lor] = val;
}

// T2[k][i][j] = img[i][j][k]  (for axis 2 vector path)
__global__ __launch_bounds__(256) void transpose_kernel(const float* __restrict__ in,
                                                        float* __restrict__ outT)
{
    int o = blockIdx.x * 256 + threadIdx.x;       // o = k*16384 + i*128 + j
    int j = o & 127, i = (o >> 7) & 127, k = o >> 14;
    outT[o] = in[i * 16384 + j * 128 + k];
}

extern "C" void kernel_launch(void* const* d_in, const int* in_sizes, int n_in,
                              void* d_out, int out_size, void* d_ws, size_t ws_size,
                              hipStream_t stream) {
    const float* img   = (const float*)d_in[0];
    const float* xlors = (const float*)d_in[1];
    const float* ylors = (const float*)d_in[2];
    const float* zlors = (const float*)d_in[3];
    float* out = (float*)d_out;

    int n = in_sizes[1] / 6;
    dim3 block(256);
    dim3 grid(((size_t)n * CHUNKS + 255) / 256);

    constexpr size_t IMG_ELEMS = 128 * 128 * 128;
    bool useT = ws_size >= IMG_ELEMS * sizeof(float);

    proj_kernel<0, true><<<grid, block, 0, stream>>>(img, xlors, out, n);
    proj_kernel<1, true><<<grid, block, 0, stream>>>(img, ylors, out, n);
    if (useT) {
        float* T2 = (float*)d_ws;
        transpose_kernel<<<IMG_ELEMS / 256, block, 0, stream>>>(img, T2);
        proj_kernel<2, true><<<grid, block, 0, stream>>>(T2, zlors, out, n);
    } else {
        proj_kernel<2, false><<<grid, block, 0, stream>>>(img, zlors, out, n);
    }
}

// Round 4
// 770.603 us; speedup vs baseline: 7.2900x; 2.5245x over previous
//
#include <hip/hip_runtime.h>
#include <math.h>

constexpr float DXC    = 3.125f;                              // 400/128
constexpr float INV_DX = 1.0f / 3.125f;
constexpr float XMINC  = -200.0f;
constexpr float KW2    = 9.0f * 3.14159265358979323846f;      // cutoff^2
constexpr float NEGL2  = -(2.0f / KW2) * 1.4426950408889634f; // exp2 scale
constexpr float MARG   = 1.2017f;                             // support cover margin

constexpr int TPB = 1024;   // threads per block = LORs per block
constexpr int LPB = 1024;

// round-to-nearest-even bf16, packed as two halves of a dword
__device__ inline unsigned bf16_rn(float x) {
    unsigned u = __float_as_uint(x);
    return (u + 0x7fffu + ((u >> 16) & 1u)) >> 16;
}
__device__ inline unsigned pk_bf16(float x, float y) {
    return bf16_rn(x) | (bf16_rn(y) << 16);
}

// Slice layouts (slice k as 128x128 row-major [i][j]):
// AXIS 0: img[k][i][j]            contiguous
// AXIS 1: img[i][k][j]            rows contiguous (128 floats)
// AXIS 2: T2[k][i][j] if TP else img[i][j][k] (strided fallback)
template <int AXIS, bool TP>
__device__ inline void stage_issue(const float* __restrict__ img, int k, int tid,
                                   float4 st[4]) {
#pragma unroll
    for (int c = 0; c < 4; ++c) {
        int f4 = tid + TPB * c;        // float4 index in slice [0,4096)
        int fl = f4 << 2;              // float index [0,16384)
        if (AXIS == 2 && !TP) {
            int i = fl >> 7, j = fl & 127;
            const float* p = img + (i << 14) + (j << 7) + k;
            st[c] = make_float4(p[0], p[128], p[256], p[384]);
        } else {
            int off;
            if (AXIS == 1) off = ((fl >> 7) << 14) | (k << 7) | (fl & 127);
            else           off = (k << 14) | fl;
            st[c] = *reinterpret_cast<const float4*>(img + off);
        }
    }
}

__device__ inline void stage_write(const float4 st[4], ushort* slb, int tid) {
    uint* w = reinterpret_cast<uint*>(slb);
#pragma unroll
    for (int c = 0; c < 4; ++c) {
        int f4 = tid + TPB * c;
        w[f4 * 2]     = pk_bf16(st[c].x, st[c].y);
        w[f4 * 2 + 1] = pk_bf16(st[c].z, st[c].w);
    }
}

template <int AXIS, bool TP>
__device__ void proj_axis(ushort (*sl)[16384], const float* __restrict__ imgA,
                          const float* __restrict__ lors, float* __restrict__ out,
                          int n, int blk)
{
    const int tid = threadIdx.x;
    const int lor = blk * LPB + tid;
    const bool active = lor < n;
    const int lorc = active ? lor : n - 1;

    const float* l = lors + (size_t)lorc * 6;
    float l0 = l[0], l1 = l[1], l2 = l[2], l3 = l[3], l4 = l[4], l5 = l[5];
    float p0x, p0y, p0z, p1x, p1y, p1z;
    if (AXIS == 0)      { p0x = l1; p0y = l2; p0z = l0; p1x = l4; p1y = l5; p1z = l3; }
    else if (AXIS == 1) { p0x = l0; p0y = l2; p0z = l1; p1x = l3; p1y = l5; p1z = l4; }
    else                { p0x = l0; p0y = l1; p0z = l2; p1x = l3; p1y = l4; p1z = l5; }

    float dvx = p1x - p0x, dvy = p1y - p0y, dvz = p1z - p0z;
    float L     = sqrtf(dvx * dvx + dvy * dvy + dvz * dvz);
    float pathL = DXC * L / fabsf(dvz);
    float invdz = 1.0f / dvz;

    // affine per-LOR coefficients: u(t), v(t), t(zc)
    float dux = dvx * INV_DX, ux0 = (p0x - XMINC) * INV_DX;
    float dvyS = dvy * INV_DX, vy0 = (p0y - XMINC) * INV_DX;
    float tzs = invdz, tz0 = -p0z * invdz;
    float acc = 0.0f;

    {   // prologue: stage slice 0
        float4 st[4];
        stage_issue<AXIS, TP>(imgA, 0, tid, st);
        stage_write(st, sl[0], tid);
    }
    __syncthreads();

    for (int k = 0; k < 128; ++k) {
        const ushort* sbuf = sl[k & 1];
        float4 st2[4];
        if (k < 127) stage_issue<AXIS, TP>(imgA, k + 1, tid, st2);  // issue early

        float zc = fmaf((float)k, DXC, XMINC + 0.5f * DXC);
        float t  = fmaf(zc, tzs, tz0);
        float u  = fmaf(t, dux, ux0);
        float v  = fmaf(t, dvyS, vy0);

        float fiu = floorf(u + MARG);
        float fjv = floorf(v + MARG);
        int is  = (int)fiu - 3;
        int jsn = (int)fjv - 3;
        int js0 = min(max(jsn & ~1, 0), 122);   // 6-col cover, dword aligned

        // column weights (6 cols js0..js0+5, all in-image)
        float dy0 = ((float)js0 + 0.5f - v) * DXC;
        float eb[6], br[6];
#pragma unroll
        for (int m = 0; m < 6; ++m) {
            float dyp = dy0 + (float)m * DXC;
            float b = dyp * dyp;
            br[m] = b;
            eb[m] = exp2f(b * NEGL2);
        }

        float du0 = (fiu - u - 2.5f) * DXC;     // ((float)is + 0.5 - u)*DXC
        const uint* s32 = reinterpret_cast<const uint*>(sbuf);
        int dwc = js0 >> 1;
#pragma unroll
        for (int r = 0; r < 4; ++r) {
            int ii = is + r;
            float dxp = du0 + (float)r * DXC;
            float a = dxp * dxp;
            float ea = ((unsigned)ii < 128u) ? exp2f(a * NEGL2) : 0.0f;
            float thr = KW2 - a;                // gate: br <= thr  <=>  a+b <= KW2
            int dw = min(max(ii, 0), 127) * 64 + dwc;
            uint d0 = s32[dw], d1 = s32[dw + 1], d2 = s32[dw + 2];
            float w0 = __uint_as_float(d0 << 16);
            float w1 = __uint_as_float(d0 & 0xffff0000u);
            float w2 = __uint_as_float(d1 << 16);
            float w3 = __uint_as_float(d1 & 0xffff0000u);
            float w4 = __uint_as_float(d2 << 16);
            float w5 = __uint_as_float(d2 & 0xffff0000u);
            float rs = 0.0f;
            rs = fmaf((br[0] <= thr) ? eb[0] : 0.0f, w0, rs);
            rs = fmaf((br[1] <= thr) ? eb[1] : 0.0f, w1, rs);
            rs = fmaf((br[2] <= thr) ? eb[2] : 0.0f, w2, rs);
            rs = fmaf((br[3] <= thr) ? eb[3] : 0.0f, w3, rs);
            rs = fmaf((br[4] <= thr) ? eb[4] : 0.0f, w4, rs);
            rs = fmaf((br[5] <= thr) ? eb[5] : 0.0f, w5, rs);
            acc = fmaf(ea, rs, acc);
        }

        if (k < 127) {
            stage_write(st2, sl[(k & 1) ^ 1], tid);
            __syncthreads();
        }
    }

    if (active) out[lor] = acc * pathL;
}

template <bool TP>
__global__ __launch_bounds__(TPB, 4) void proj_fused(const float* __restrict__ img,
                                                     const float* __restrict__ T2,
                                                     const float* __restrict__ xl,
                                                     const float* __restrict__ yl,
                                                     const float* __restrict__ zl,
                                                     float* __restrict__ out,
                                                     int n, int nblk)
{
    __shared__ ushort sl[2][16384];   // double-buffered bf16 slice
    int bx = blockIdx.x;
    int axis = bx / nblk, blk = bx - axis * nblk;
    if (axis == 0)      proj_axis<0, true>(sl, img, xl, out, n, blk);
    else if (axis == 1) proj_axis<1, true>(sl, img, yl, out + n, n, blk);
    else                proj_axis<2, TP>(sl, TP ? T2 : img, zl, out + 2 * (size_t)n, n, blk);
}

// T2[k][i][j] = img[i][j][k]
__global__ __launch_bounds__(256) void transpose_kernel(const float* __restrict__ in,
                                                        float* __restrict__ outT)
{
    int o = blockIdx.x * 256 + threadIdx.x;       // o = k*16384 + i*128 + j
    int j = o & 127, i = (o >> 7) & 127, k = o >> 14;
    outT[o] = in[i * 16384 + j * 128 + k];
}

extern "C" void kernel_launch(void* const* d_in, const int* in_sizes, int n_in,
                              void* d_out, int out_size, void* d_ws, size_t ws_size,
                              hipStream_t stream) {
    const float* img   = (const float*)d_in[0];
    const float* xlors = (const float*)d_in[1];
    const float* ylors = (const float*)d_in[2];
    const float* zlors = (const float*)d_in[3];
    float* out = (float*)d_out;

    int n = in_sizes[1] / 6;
    int nblk = (n + LPB - 1) / LPB;

    constexpr size_t IMG_ELEMS = 128 * 128 * 128;
    bool useT = ws_size >= IMG_ELEMS * sizeof(float);

    if (useT) {
        float* T2 = (float*)d_ws;
        transpose_kernel<<<IMG_ELEMS / 256, 256, 0, stream>>>(img, T2);
        proj_fused<true><<<3 * nblk, TPB, 0, stream>>>(img, T2, xlors, ylors, zlors, out, n, nblk);
    } else {
        proj_fused<false><<<3 * nblk, TPB, 0, stream>>>(img, nullptr, xlors, ylors, zlors, out, n, nblk);
    }
}

// Round 5
// 466.920 us; speedup vs baseline: 12.0315x; 1.6504x over previous
//
#include <hip/hip_runtime.h>
#include <math.h>

constexpr float DXC    = 3.125f;                              // 400/128
constexpr float INV_DX = 0.32f;                               // 1/3.125
constexpr float XMINC  = -200.0f;
constexpr float KW2    = 9.0f * 3.14159265358979323846f;      // cutoff^2
constexpr float NEGL2  = -(2.0f / KW2) * 1.4426950408889634f; // exp2 scale
constexpr float MARG   = 1.2017f;                             // support cover margin

constexpr int TPB    = 1024;   // threads per block = LORs per block
constexpr int LPB    = 1024;
constexpr int KSPLIT = 4;      // k-range split across blocks
constexpr int KCH    = 128 / KSPLIT;

// round-to-nearest-even bf16
__device__ inline unsigned bf16_rn(float x) {
    unsigned u = __float_as_uint(x);
    return (u + 0x7fffu + ((u >> 16) & 1u)) >> 16;
}
__device__ inline unsigned pk_bf16(float x, float y) {
    return bf16_rn(x) | (bf16_rn(y) << 16);
}

// ---- prep: build bf16 volumes V0/V1/V2 with slice-contiguous [k][i][j] layouts
// AXIS 0: val = image[k][i][j]  -> V0[o] = img[o]
// AXIS 1: val = image[i][k][j]  -> V1[b][a][c] = image[a][b][c]
// AXIS 2: val = image[i][j][k]  -> V2 (output-indexed) V2[k][i][j] = image[i][j][k]
__global__ __launch_bounds__(256) void prep_kernel(const float* __restrict__ img,
                                                   ushort* __restrict__ V0,
                                                   ushort* __restrict__ V1,
                                                   ushort* __restrict__ V2) {
    int o = blockIdx.x * 256 + threadIdx.x;           // 0 .. 128^3
    float x = img[o];
    unsigned h = bf16_rn(x);
    V0[o] = (ushort)h;
    int c = o & 127, b = (o >> 7) & 127, a = o >> 14;
    V1[(b << 14) | (a << 7) | c] = (ushort)h;
    // output-indexed for V2: o = k*16384 + i*128 + j
    int j = o & 127, i = (o >> 7) & 127, k = o >> 14;
    V2[o] = (ushort)bf16_rn(img[(i << 14) | (j << 7) | k]);
}

__global__ __launch_bounds__(1024) void zero_kernel(float* __restrict__ out, int m) {
    int i = blockIdx.x * 1024 + threadIdx.x;
    if (i < m) out[i] = 0.0f;
}

// ---- staging ----
// PRE path: async DMA of one bf16 slice (32KB) global->LDS, linear copy.
__device__ inline void stage_pre(const ushort* __restrict__ V, int k, int tid,
                                 ushort* slb) {
    const char* src = (const char*)(V + ((size_t)k << 14));
    char* dst = (char*)slb;
    int wbase = (tid >> 6) << 10;           // wave * 1024 bytes
    int lane16 = (tid & 63) << 4;
#pragma unroll
    for (int c = 0; c < 2; ++c) {
        int half = c << 14;                 // 0 / 16384
        __builtin_amdgcn_global_load_lds(
            (__attribute__((address_space(1))) void*)(const_cast<char*>(src + half + wbase + lane16)),
            (__attribute__((address_space(3))) void*)(dst + half + wbase),
            16, 0, 0);
    }
}

// Fallback path (no ws): fp32 global -> regs -> convert -> LDS (R4 scheme)
template <int AXIS>
__device__ inline void stage_issue(const float* __restrict__ img, int k, int tid,
                                   float4 st[4]) {
#pragma unroll
    for (int c = 0; c < 4; ++c) {
        int f4 = tid + TPB * c;        // float4 index in slice [0,4096)
        int fl = f4 << 2;              // float index [0,16384)
        if (AXIS == 2) {
            int i = fl >> 7, j = fl & 127;
            const float* p = img + (i << 14) + (j << 7) + k;
            st[c] = make_float4(p[0], p[128], p[256], p[384]);
        } else {
            int off;
            if (AXIS == 1) off = ((fl >> 7) << 14) | (k << 7) | (fl & 127);
            else           off = (k << 14) | fl;
            st[c] = *reinterpret_cast<const float4*>(img + off);
        }
    }
}

__device__ inline void stage_write(const float4 st[4], ushort* slb, int tid) {
    uint* w = reinterpret_cast<uint*>(slb);
#pragma unroll
    for (int c = 0; c < 4; ++c) {
        int f4 = tid + TPB * c;
        w[f4 * 2]     = pk_bf16(st[c].x, st[c].y);
        w[f4 * 2 + 1] = pk_bf16(st[c].z, st[c].w);
    }
}

template <int AXIS, bool PRE>
__device__ void proj_axis(ushort (*sl)[16384],
                          const ushort* __restrict__ V,
                          const float*  __restrict__ imgF,
                          const float*  __restrict__ lors,
                          float* __restrict__ out, int n, int blk, int ks)
{
    const int tid = threadIdx.x;
    const int lor = blk * LPB + tid;
    const bool active = lor < n;
    const int lorc = active ? lor : n - 1;

    const float* l = lors + (size_t)lorc * 6;
    float l0 = l[0], l1 = l[1], l2 = l[2], l3 = l[3], l4 = l[4], l5 = l[5];
    float p0x, p0y, p0z, p1x, p1y, p1z;
    if (AXIS == 0)      { p0x = l1; p0y = l2; p0z = l0; p1x = l4; p1y = l5; p1z = l3; }
    else if (AXIS == 1) { p0x = l0; p0y = l2; p0z = l1; p1x = l3; p1y = l5; p1z = l4; }
    else                { p0x = l0; p0y = l1; p0z = l2; p1x = l3; p1y = l4; p1z = l5; }

    float dvx = p1x - p0x, dvy = p1y - p0y, dvz = p1z - p0z;
    float L     = sqrtf(dvx * dvx + dvy * dvy + dvz * dvz);
    float pathL = DXC * L / fabsf(dvz);
    float invdz = 1.0f / dvz;

    // affine per-LOR coefficients: t(zc), u(t), v(t)
    float dux  = dvx * INV_DX, ux0 = (p0x - XMINC) * INV_DX;
    float dvyS = dvy * INV_DX, vy0 = (p0y - XMINC) * INV_DX;
    float tzs = invdz, tz0 = -p0z * invdz;
    // NOTE: t in [0,1] guard is vacuous here: each axis's LOR set spans the
    // full cube along its own axis by construction (endpoints at +-half).
    float acc = 0.0f;

    const int k0 = ks * KCH, k1 = k0 + KCH;

    {   // prologue: stage first slice
        if (PRE) {
            stage_pre(V, k0, tid, sl[k0 & 1]);
        } else {
            float4 st[4];
            stage_issue<AXIS>(imgF, k0, tid, st);
            stage_write(st, sl[k0 & 1], tid);
        }
    }
    __syncthreads();

    for (int k = k0; k < k1; ++k) {
        const ushort* sbuf = sl[k & 1];
        float4 st2[4];
        if (k < k1 - 1) {                       // issue next-slice loads early
            if (PRE) stage_pre(V, k + 1, tid, sl[(k & 1) ^ 1]);
            else     stage_issue<AXIS>(imgF, k + 1, tid, st2);
        }

        float zc = fmaf((float)k, DXC, XMINC + 0.5f * DXC);
        float t  = fmaf(zc, tzs, tz0);
        float u  = fmaf(t, dux, ux0);
        float v  = fmaf(t, dvyS, vy0);

        float fiu = floorf(u + MARG);
        float fjv = floorf(v + MARG);
        int is  = (int)fiu - 3;
        int jsn = (int)fjv - 3;
        int js0 = min(max(jsn & ~1, 0), 122);   // 6-col cover, dword aligned

        float dy0 = ((float)js0 + 0.5f - v) * DXC;
        float eb[6], br[6];
#pragma unroll
        for (int m = 0; m < 6; ++m) {
            float dyp = dy0 + (float)m * DXC;
            float b = dyp * dyp;
            br[m] = b;
            eb[m] = exp2f(b * NEGL2);
        }

        float du0 = (fiu - u - 2.5f) * DXC;     // ((float)is + 0.5 - u)*DXC
        const uint* s32 = reinterpret_cast<const uint*>(sbuf);
        int dwc = js0 >> 1;
#pragma unroll
        for (int r = 0; r < 4; ++r) {
            int ii = is + r;
            float dxp = du0 + (float)r * DXC;
            float a = dxp * dxp;
            float ea = ((unsigned)ii < 128u) ? exp2f(a * NEGL2) : 0.0f;
            float thr = KW2 - a;                // gate: b <= thr <=> a+b <= KW2
            int dw = min(max(ii, 0), 127) * 64 + dwc;
            uint d0 = s32[dw], d1 = s32[dw + 1], d2 = s32[dw + 2];
            float w0 = __uint_as_float(d0 << 16);
            float w1 = __uint_as_float(d0 & 0xffff0000u);
            float w2 = __uint_as_float(d1 << 16);
            float w3 = __uint_as_float(d1 & 0xffff0000u);
            float w4 = __uint_as_float(d2 << 16);
            float w5 = __uint_as_float(d2 & 0xffff0000u);
            float rs = 0.0f;
            rs = fmaf((br[0] <= thr) ? eb[0] : 0.0f, w0, rs);
            rs = fmaf((br[1] <= thr) ? eb[1] : 0.0f, w1, rs);
            rs = fmaf((br[2] <= thr) ? eb[2] : 0.0f, w2, rs);
            rs = fmaf((br[3] <= thr) ? eb[3] : 0.0f, w3, rs);
            rs = fmaf((br[4] <= thr) ? eb[4] : 0.0f, w4, rs);
            rs = fmaf((br[5] <= thr) ? eb[5] : 0.0f, w5, rs);
            acc = fmaf(ea, rs, acc);
        }

        if (k < k1 - 1) {
            if (!PRE) stage_write(st2, sl[(k & 1) ^ 1], tid);
            __syncthreads();                    // drains vmcnt -> next slice ready
        }
    }

    if (active) atomicAdd(out + lor, acc * pathL);
}

template <bool PRE>
__global__ __launch_bounds__(TPB, 8) void proj_fused(const float* __restrict__ img,
                                                     const ushort* __restrict__ V0,
                                                     const ushort* __restrict__ V1,
                                                     const ushort* __restrict__ V2,
                                                     const float* __restrict__ xl,
                                                     const float* __restrict__ yl,
                                                     const float* __restrict__ zl,
                                                     float* __restrict__ out,
                                                     int n, int nblk)
{
    __shared__ ushort sl[2][16384];   // double-buffered bf16 slice (64 KiB)
    int per = nblk * KSPLIT;
    int axis = blockIdx.x / per;
    int r = blockIdx.x - axis * per;
    int blk = r >> 2;                 // KSPLIT = 4
    int ks  = r & 3;
    if (axis == 0)      proj_axis<0, PRE>(sl, V0, img, xl, out, n, blk, ks);
    else if (axis == 1) proj_axis<1, PRE>(sl, V1, img, yl, out + n, n, blk, ks);
    else                proj_axis<2, PRE>(sl, V2, img, zl, out + 2 * (size_t)n, n, blk, ks);
}

extern "C" void kernel_launch(void* const* d_in, const int* in_sizes, int n_in,
                              void* d_out, int out_size, void* d_ws, size_t ws_size,
                              hipStream_t stream) {
    const float* img   = (const float*)d_in[0];
    const float* xlors = (const float*)d_in[1];
    const float* ylors = (const float*)d_in[2];
    const float* zlors = (const float*)d_in[3];
    float* out = (float*)d_out;

    int n = in_sizes[1] / 6;
    int nblk = (n + LPB - 1) / LPB;
    int m = 3 * n;

    zero_kernel<<<(m + 1023) / 1024, 1024, 0, stream>>>(out, m);

    constexpr size_t VOL = 128 * 128 * 128;
    bool pre = ws_size >= 3 * VOL * sizeof(ushort);
    int grid = 3 * nblk * KSPLIT;

    if (pre) {
        ushort* V0 = (ushort*)d_ws;
        ushort* V1 = V0 + VOL;
        ushort* V2 = V1 + VOL;
        prep_kernel<<<VOL / 256, 256, 0, stream>>>(img, V0, V1, V2);
        proj_fused<true><<<grid, TPB, 0, stream>>>(img, V0, V1, V2,
                                                   xlors, ylors, zlors, out, n, nblk);
    } else {
        proj_fused<false><<<grid, TPB, 0, stream>>>(img, nullptr, nullptr, nullptr,
                                                    xlors, ylors, zlors, out, n, nblk);
    }
}

// Round 6
// 381.161 us; speedup vs baseline: 14.7385x; 1.2250x over previous
//
#include <hip/hip_runtime.h>
#include <math.h>

constexpr float DXC    = 3.125f;                              // 400/128
constexpr float INV_DX = 0.32f;                               // 1/3.125
constexpr float XMINC  = -200.0f;
constexpr float KW2    = 9.0f * 3.14159265358979323846f;      // cutoff^2
constexpr float NEGL2  = -(2.0f / KW2) * 1.4426950408889634f; // exp2 scale
constexpr float MARG   = 1.2017f;                             // support cover margin
constexpr float DXC2   = DXC * DXC;                           // 9.765625
constexpr float C2     = 2.0f * DXC2;                         // 19.53125
constexpr float TWODXC = 2.0f * DXC;                          // 6.25

constexpr int TPB    = 1024;   // threads per block = LORs per block
constexpr int LPB    = 1024;
constexpr int KSPLIT = 4;      // k-range split across blocks
constexpr int KCH    = 128 / KSPLIT;

// round-to-nearest-even bf16
__device__ inline unsigned bf16_rn(float x) {
    unsigned u = __float_as_uint(x);
    return (u + 0x7fffu + ((u >> 16) & 1u)) >> 16;
}
__device__ inline unsigned pk_bf16(float x, float y) {
    return bf16_rn(x) | (bf16_rn(y) << 16);
}

// ---- prep: build bf16 volumes V0/V1/V2 with slice-contiguous [k][i][j] layouts
__global__ __launch_bounds__(256) void prep_kernel(const float* __restrict__ img,
                                                   ushort* __restrict__ V0,
                                                   ushort* __restrict__ V1,
                                                   ushort* __restrict__ V2) {
    int o = blockIdx.x * 256 + threadIdx.x;           // 0 .. 128^3
    float x = img[o];
    unsigned h = bf16_rn(x);
    V0[o] = (ushort)h;
    int c = o & 127, b = (o >> 7) & 127, a = o >> 14;
    V1[(b << 14) | (a << 7) | c] = (ushort)h;
    // output-indexed for V2: o = k*16384 + i*128 + j  -> img[i][j][k]
    int j = o & 127, i = (o >> 7) & 127, k = o >> 14;
    V2[o] = (ushort)bf16_rn(img[(i << 14) | (j << 7) | k]);
}

__global__ __launch_bounds__(1024) void zero_kernel(float* __restrict__ out, int m) {
    int i = blockIdx.x * 1024 + threadIdx.x;
    if (i < m) out[i] = 0.0f;
}

// ---- staging ----
// PRE path: async DMA of one bf16 slice (32KB) global->LDS, linear copy.
__device__ inline void stage_pre(const ushort* __restrict__ V, int k, int tid,
                                 ushort* slb) {
    const char* src = (const char*)(V + ((size_t)k << 14));
    char* dst = (char*)slb;
    int wbase = (tid >> 6) << 10;           // wave * 1024 bytes
    int lane16 = (tid & 63) << 4;
#pragma unroll
    for (int c = 0; c < 2; ++c) {
        int half = c << 14;                 // 0 / 16384
        __builtin_amdgcn_global_load_lds(
            (__attribute__((address_space(1))) void*)(const_cast<char*>(src + half + wbase + lane16)),
            (__attribute__((address_space(3))) void*)(dst + half + wbase),
            16, 0, 0);
    }
}

// Fallback path (no ws): fp32 global -> regs -> convert -> LDS
template <int AXIS>
__device__ inline void stage_issue(const float* __restrict__ img, int k, int tid,
                                   float4 st[4]) {
#pragma unroll
    for (int c = 0; c < 4; ++c) {
        int f4 = tid + TPB * c;
        int fl = f4 << 2;
        if (AXIS == 2) {
            int i = fl >> 7, j = fl & 127;
            const float* p = img + (i << 14) + (j << 7) + k;
            st[c] = make_float4(p[0], p[128], p[256], p[384]);
        } else {
            int off;
            if (AXIS == 1) off = ((fl >> 7) << 14) | (k << 7) | (fl & 127);
            else           off = (k << 14) | fl;
            st[c] = *reinterpret_cast<const float4*>(img + off);
        }
    }
}

__device__ inline void stage_write(const float4 st[4], ushort* slb, int tid) {
    uint* w = reinterpret_cast<uint*>(slb);
#pragma unroll
    for (int c = 0; c < 4; ++c) {
        int f4 = tid + TPB * c;
        w[f4 * 2]     = pk_bf16(st[c].x, st[c].y);
        w[f4 * 2 + 1] = pk_bf16(st[c].z, st[c].w);
    }
}

template <int AXIS, bool PRE>
__device__ void proj_axis(ushort (*sl)[16384],
                          const ushort* __restrict__ V,
                          const float*  __restrict__ imgF,
                          const float*  __restrict__ lors,
                          float* __restrict__ out, int n, int blk, int ks)
{
    const int tid = threadIdx.x;
    const int lor = blk * LPB + tid;
    const bool active = lor < n;
    const int lorc = active ? lor : n - 1;

    const float* l = lors + (size_t)lorc * 6;
    float l0 = l[0], l1 = l[1], l2 = l[2], l3 = l[3], l4 = l[4], l5 = l[5];
    float p0x, p0y, p0z, p1x, p1y, p1z;
    if (AXIS == 0)      { p0x = l1; p0y = l2; p0z = l0; p1x = l4; p1y = l5; p1z = l3; }
    else if (AXIS == 1) { p0x = l0; p0y = l2; p0z = l1; p1x = l3; p1y = l5; p1z = l4; }
    else                { p0x = l0; p0y = l1; p0z = l2; p1x = l3; p1y = l4; p1z = l5; }

    float dvx = p1x - p0x, dvy = p1y - p0y, dvz = p1z - p0z;
    float L     = sqrtf(dvx * dvx + dvy * dvy + dvz * dvz);
    float pathL = DXC * L / fabsf(dvz);
    float invdz = 1.0f / dvz;

    // u(k), v(k) are affine in k -> incremental updates
    float dux  = dvx * INV_DX, ux0 = (p0x - XMINC) * INV_DX;
    float dvyS = dvy * INV_DX, vy0 = (p0y - XMINC) * INV_DX;
    float tzs = invdz, tz0 = -p0z * invdz;
    // t in [0,1] is vacuous: per-axis LOR endpoints sit on the +-half faces.

    const int k0 = ks * KCH, k1 = k0 + KCH;

    float dt = DXC * tzs;
    float cu = dux * dt, cv = dvyS * dt;
    float zc0 = fmaf((float)k0, DXC, XMINC + 0.5f * DXC);
    float t0  = fmaf(zc0, tzs, tz0);
    float u   = fmaf(t0, dux, ux0);
    float v   = fmaf(t0, dvyS, vy0);

    const float SRR = exp2f(C2 * NEGL2);   // const ratio-of-ratios (per-thread once)
    float acc = 0.0f;

    {   // prologue: stage first slice
        if (PRE) {
            stage_pre(V, k0, tid, sl[k0 & 1]);
        } else {
            float4 st[4];
            stage_issue<AXIS>(imgF, k0, tid, st);
            stage_write(st, sl[k0 & 1], tid);
        }
    }
    __syncthreads();

    for (int k = k0; k < k1; ++k) {
        const ushort* sbuf = sl[k & 1];
        float4 st2[4];
        if (k < k1 - 1) {                       // issue next-slice loads early
            if (PRE) stage_pre(V, k + 1, tid, sl[(k & 1) ^ 1]);
            else     stage_issue<AXIS>(imgF, k + 1, tid, st2);
        }

        // ---- column (j) weights: 4-col true-support window, ratio-chain exps
        int jsn = (int)floorf(v + MARG) - 3;
        int e0  = min(max(jsn, 0), 124);
        float dy0 = ((float)e0 + 0.5f - v) * DXC;
        float b0 = dy0 * dy0;
        float gb = fmaf(TWODXC, dy0, DXC2);
        float b1 = b0 + gb, gb1 = gb + C2;
        float b2 = b1 + gb1, gb2 = gb1 + C2;
        float b3 = b2 + gb2;
        float eb0 = exp2f(b0 * NEGL2);
        float rb  = exp2f(gb * NEGL2);
        float eb1 = eb0 * rb; rb *= SRR;
        float eb2 = eb1 * rb; rb *= SRR;
        float eb3 = eb2 * rb;

        // ---- row (i) weights
        int is  = (int)floorf(u + MARG) - 3;
        int i0c = min(max(is, 0), 124);
        float du0 = ((float)i0c + 0.5f - u) * DXC;
        float a0 = du0 * du0;
        float ga = fmaf(TWODXC, du0, DXC2);
        float a1 = a0 + ga, ga1 = ga + C2;
        float a2 = a1 + ga1, ga2 = ga1 + C2;
        float a3 = a2 + ga2;
        float ea[4], thr[4];
        ea[0] = exp2f(a0 * NEGL2);
        float ra = exp2f(ga * NEGL2);
        ea[1] = ea[0] * ra; ra *= SRR;
        ea[2] = ea[1] * ra; ra *= SRR;
        ea[3] = ea[2] * ra;
        thr[0] = KW2 - a0; thr[1] = KW2 - a1; thr[2] = KW2 - a2; thr[3] = KW2 - a3;

        // ---- gather 4x4 patch: 3 dwords/row, funnel-extract 4 bf16
        const uint* s32 = reinterpret_cast<const uint*>(sbuf);
        int q0 = e0 >> 1;
        int q2 = min(q0 + 2, 63);               // 3rd dword unused when e0 even
        int sh = (e0 & 1) << 4;
        int rowdw = (i0c << 6) + q0;
#pragma unroll
        for (int r = 0; r < 4; ++r) {
            const uint* sr = s32 + rowdw + (r << 6);
            uint d0 = sr[0], d1 = sr[1], d2 = sr[q2 - q0];
            uint p01 = (uint)(((((unsigned long long)d1) << 32) | d0) >> sh);
            uint p23 = (uint)(((((unsigned long long)d2) << 32) | d1) >> sh);
            float w0 = __uint_as_float(p01 << 16);
            float w1 = __uint_as_float(p01 & 0xffff0000u);
            float w2 = __uint_as_float(p23 << 16);
            float w3 = __uint_as_float(p23 & 0xffff0000u);
            float tr = thr[r];
            float rs;
            rs = __fmul_rn((b0 <= tr) ? eb0 : 0.0f, w0);
            rs = fmaf((b1 <= tr) ? eb1 : 0.0f, w1, rs);
            rs = fmaf((b2 <= tr) ? eb2 : 0.0f, w2, rs);
            rs = fmaf((b3 <= tr) ? eb3 : 0.0f, w3, rs);
            acc = fmaf(ea[r], rs, acc);
        }

        u += cu; v += cv;

        if (k < k1 - 1) {
            if (!PRE) stage_write(st2, sl[(k & 1) ^ 1], tid);
            __syncthreads();                    // drains vmcnt -> next slice ready
        }
    }

    if (active) atomicAdd(out + lor, acc * pathL);
}

template <bool PRE>
__global__ __launch_bounds__(TPB, 8) void proj_fused(const float* __restrict__ img,
                                                     const ushort* __restrict__ V0,
                                                     const ushort* __restrict__ V1,
                                                     const ushort* __restrict__ V2,
                                                     const float* __restrict__ xl,
                                                     const float* __restrict__ yl,
                                                     const float* __restrict__ zl,
                                                     float* __restrict__ out,
                                                     int n, int nblk)
{
    __shared__ ushort sl[2][16384];   // double-buffered bf16 slice (64 KiB)
    int per = nblk * KSPLIT;
    int axis = blockIdx.x / per;
    int r = blockIdx.x - axis * per;
    int blk = r >> 2;                 // KSPLIT = 4
    int ks  = r & 3;
    if (axis == 0)      proj_axis<0, PRE>(sl, V0, img, xl, out, n, blk, ks);
    else if (axis == 1) proj_axis<1, PRE>(sl, V1, img, yl, out + n, n, blk, ks);
    else                proj_axis<2, PRE>(sl, V2, img, zl, out + 2 * (size_t)n, n, blk, ks);
}

extern "C" void kernel_launch(void* const* d_in, const int* in_sizes, int n_in,
                              void* d_out, int out_size, void* d_ws, size_t ws_size,
                              hipStream_t stream) {
    const float* img   = (const float*)d_in[0];
    const float* xlors = (const float*)d_in[1];
    const float* ylors = (const float*)d_in[2];
    const float* zlors = (const float*)d_in[3];
    float* out = (float*)d_out;

    int n = in_sizes[1] / 6;
    int nblk = (n + LPB - 1) / LPB;
    int m = 3 * n;

    zero_kernel<<<(m + 1023) / 1024, 1024, 0, stream>>>(out, m);

    constexpr size_t VOL = 128 * 128 * 128;
    bool pre = ws_size >= 3 * VOL * sizeof(ushort);
    int grid = 3 * nblk * KSPLIT;

    if (pre) {
        ushort* V0 = (ushort*)d_ws;
        ushort* V1 = V0 + VOL;
        ushort* V2 = V1 + VOL;
        prep_kernel<<<VOL / 256, 256, 0, stream>>>(img, V0, V1, V2);
        proj_fused<true><<<grid, TPB, 0, stream>>>(img, V0, V1, V2,
                                                   xlors, ylors, zlors, out, n, nblk);
    } else {
        proj_fused<false><<<grid, TPB, 0, stream>>>(img, nullptr, nullptr, nullptr,
                                                    xlors, ylors, zlors, out, n, nblk);
    }
}

// Round 7
// 322.223 us; speedup vs baseline: 17.4343x; 1.1829x over previous
//
#include <hip/hip_runtime.h>
#include <math.h>

constexpr float DXC    = 3.125f;                              // 400/128
constexpr float INV_DX = 0.32f;                               // 1/3.125
constexpr float XMINC  = -200.0f;
constexpr float KW2    = 9.0f * 3.14159265358979323846f;      // cutoff^2 (mm^2)
constexpr float DXC2   = DXC * DXC;                           // 9.765625
constexpr float KW2C   = KW2 / DXC2;                          // cutoff^2 in cell^2 = 2.89529
constexpr float NEGL2C = -(2.0f / KW2) * 1.4426950408889634f * DXC2; // exp2 scale, cell^2 arg
constexpr float WOFF   = 1.7983f;                             // 3 - MARG

constexpr int TPB    = 1024;   // threads per block = LORs per block
constexpr int LPB    = 1024;
constexpr int KSPLIT = 4;      // k-range split across blocks
constexpr int KCH    = 128 / KSPLIT;
constexpr int QTAB   = 1024;   // weight-table bins over s in [0,4)

// round-to-nearest-even bf16
__device__ inline unsigned bf16_rn(float x) {
    unsigned u = __float_as_uint(x);
    return (u + 0x7fffu + ((u >> 16) & 1u)) >> 16;
}
__device__ inline unsigned pk_bf16(float x, float y) {
    return bf16_rn(x) | (bf16_rn(y) << 16);
}

// ---- prep: build bf16 volumes V0/V1/V2 with slice-contiguous [k][i][j] layouts
__global__ __launch_bounds__(256) void prep_kernel(const float* __restrict__ img,
                                                   ushort* __restrict__ V0,
                                                   ushort* __restrict__ V1,
                                                   ushort* __restrict__ V2) {
    int o = blockIdx.x * 256 + threadIdx.x;           // 0 .. 128^3
    float x = img[o];
    unsigned h = bf16_rn(x);
    V0[o] = (ushort)h;
    int c = o & 127, b = (o >> 7) & 127, a = o >> 14;
    V1[(b << 14) | (a << 7) | c] = (ushort)h;
    int j = o & 127, i = (o >> 7) & 127, k = o >> 14;
    V2[o] = (ushort)bf16_rn(img[(i << 14) | (j << 7) | k]);
}

__global__ __launch_bounds__(1024) void zero_kernel(float* __restrict__ out, int m) {
    int i = blockIdx.x * 1024 + threadIdx.x;
    if (i < m) out[i] = 0.0f;
}

// ---- staging ----
__device__ inline void stage_pre(const ushort* __restrict__ V, int k, int tid,
                                 ushort* slb) {
    const char* src = (const char*)(V + ((size_t)k << 14));
    char* dst = (char*)slb;
    int wbase = (tid >> 6) << 10;           // wave * 1024 bytes
    int lane16 = (tid & 63) << 4;
#pragma unroll
    for (int c = 0; c < 2; ++c) {
        int half = c << 14;                 // 0 / 16384
        __builtin_amdgcn_global_load_lds(
            (__attribute__((address_space(1))) void*)(const_cast<char*>(src + half + wbase + lane16)),
            (__attribute__((address_space(3))) void*)(dst + half + wbase),
            16, 0, 0);
    }
}

template <int AXIS>
__device__ inline void stage_issue(const float* __restrict__ img, int k, int tid,
                                   float4 st[4]) {
#pragma unroll
    for (int c = 0; c < 4; ++c) {
        int f4 = tid + TPB * c;
        int fl = f4 << 2;
        if (AXIS == 2) {
            int i = fl >> 7, j = fl & 127;
            const float* p = img + (i << 14) + (j << 7) + k;
            st[c] = make_float4(p[0], p[128], p[256], p[384]);
        } else {
            int off;
            if (AXIS == 1) off = ((fl >> 7) << 14) | (k << 7) | (fl & 127);
            else           off = (k << 14) | fl;
            st[c] = *reinterpret_cast<const float4*>(img + off);
        }
    }
}

__device__ inline void stage_write(const float4 st[4], ushort* slb, int tid) {
    uint* w = reinterpret_cast<uint*>(slb);
#pragma unroll
    for (int c = 0; c < 4; ++c) {
        int f4 = tid + TPB * c;
        w[f4 * 2]     = pk_bf16(st[c].x, st[c].y);
        w[f4 * 2 + 1] = pk_bf16(st[c].z, st[c].w);
    }
}

template <int AXIS, bool PRE>
__device__ void proj_axis(ushort (*sl)[16384], float4* wtab,
                          const ushort* __restrict__ V,
                          const float*  __restrict__ imgF,
                          const float*  __restrict__ lors,
                          float* __restrict__ out, int n, int blk, int ks)
{
    const int tid = threadIdx.x;
    const int lor = blk * LPB + tid;
    const bool active = lor < n;
    const int lorc = active ? lor : n - 1;

    const float* l = lors + (size_t)lorc * 6;
    float l0 = l[0], l1 = l[1], l2 = l[2], l3 = l[3], l4 = l[4], l5 = l[5];
    float p0x, p0y, p0z, p1x, p1y, p1z;
    if (AXIS == 0)      { p0x = l1; p0y = l2; p0z = l0; p1x = l4; p1y = l5; p1z = l3; }
    else if (AXIS == 1) { p0x = l0; p0y = l2; p0z = l1; p1x = l3; p1y = l5; p1z = l4; }
    else                { p0x = l0; p0y = l1; p0z = l2; p1x = l3; p1y = l4; p1z = l5; }

    float dvx = p1x - p0x, dvy = p1y - p0y, dvz = p1z - p0z;
    float L     = sqrtf(dvx * dvx + dvy * dvy + dvz * dvz);
    float pathL = DXC * L / fabsf(dvz);
    float invdz = 1.0f / dvz;

    // u(k), v(k) affine in k -> incremental
    float dux  = dvx * INV_DX, ux0 = (p0x - XMINC) * INV_DX;
    float dvyS = dvy * INV_DX, vy0 = (p0y - XMINC) * INV_DX;
    float tzs = invdz, tz0 = -p0z * invdz;
    // t in [0,1] vacuous: per-axis LOR endpoints sit on the +-half faces.

    const int k0 = ks * KCH, k1 = k0 + KCH;

    float dt = DXC * tzs;
    float cu = dux * dt, cv = dvyS * dt;
    float zc0 = fmaf((float)k0, DXC, XMINC + 0.5f * DXC);
    float t0  = fmaf(zc0, tzs, tz0);
    float u   = fmaf(t0, dux, ux0);
    float v   = fmaf(t0, dvyS, vy0);
    float acc = 0.0f;

    // prologue: issue slice-0 DMA, then fill weight table under it
    if (PRE) {
        stage_pre(V, k0, tid, sl[k0 & 1]);
    } else {
        float4 st[4];
        stage_issue<AXIS>(imgF, k0, tid, st);
        stage_write(st, sl[k0 & 1], tid);
    }
    {   // wtab[q] = weights for 4 rows at sub-window offset s=(q+0.5)*4/QTAB
        float s = ((float)tid + 0.5f) * (4.0f / (float)QTAB);
        float4 e;
        float o0 = 0.5f - s, o1 = 1.5f - s, o2 = 2.5f - s, o3 = 3.5f - s;
        e.x = exp2f(o0 * o0 * NEGL2C);
        e.y = exp2f(o1 * o1 * NEGL2C);
        e.z = exp2f(o2 * o2 * NEGL2C);
        e.w = exp2f(o3 * o3 * NEGL2C);
        wtab[tid] = e;
    }
    __syncthreads();

    for (int k = k0; k < k1; ++k) {
        const ushort* sbuf = sl[k & 1];
        float4 st2[4];
        if (k < k1 - 1) {                       // issue next-slice loads early
            if (PRE) stage_pre(V, k + 1, tid, sl[(k & 1) ^ 1]);
            else     stage_issue<AXIS>(imgF, k + 1, tid, st2);
        }

        // ---- column (j): window start + table weights + gate chain (cell units)
        float e0f = fminf(fmaxf(floorf(v - WOFF), 0.0f), 124.0f);
        int   e0  = (int)e0f;
        int   qv  = min((int)((v - e0f) * (QTAB / 4.0f)), QTAB - 1);
        float4 eb = wtab[qv];
        float db0 = e0f + 0.5f - v;
        float b0 = db0 * db0;
        float gb = fmaf(2.0f, db0, 1.0f);
        float b1 = b0 + gb, gb1 = gb + 2.0f;
        float b2 = b1 + gb1, gb2 = gb1 + 2.0f;
        float b3 = b2 + gb2;

        // ---- row (i): same structure
        float i0f = fminf(fmaxf(floorf(u - WOFF), 0.0f), 124.0f);
        int   i0c = (int)i0f;
        int   qu  = min((int)((u - i0f) * (QTAB / 4.0f)), QTAB - 1);
        float4 ea = wtab[qu];
        float da0 = i0f + 0.5f - u;
        float a0 = da0 * da0;
        float ga = fmaf(2.0f, da0, 1.0f);
        float a1 = a0 + ga, ga1 = ga + 2.0f;
        float a2 = a1 + ga1, ga2 = ga1 + 2.0f;
        float a3 = a2 + ga2;
        float thr[4] = {KW2C - a0, KW2C - a1, KW2C - a2, KW2C - a3};
        float eaa[4] = {ea.x, ea.y, ea.z, ea.w};

        // ---- gather 4x4 patch: 3 dwords/row, alignbit-extract 4 bf16
        const uint* s32 = reinterpret_cast<const uint*>(sbuf);
        int dwc = e0 >> 1;
        int o2d = min(dwc + 2, 63) - dwc;       // 3rd dword (clamped; unused if sh==0)
        int sh  = (e0 & 1) << 4;
        int rowdw = (i0c << 6) + dwc;
#pragma unroll
        for (int r = 0; r < 4; ++r) {
            const uint* sr = s32 + rowdw + (r << 6);
            uint d0 = sr[0], d1 = sr[1], d2 = sr[o2d];
            uint p01 = __builtin_amdgcn_alignbit(d1, d0, sh);
            uint p23 = __builtin_amdgcn_alignbit(d2, d1, sh);
            float w0 = __uint_as_float(p01 << 16);
            float w1 = __uint_as_float(p01 & 0xffff0000u);
            float w2 = __uint_as_float(p23 << 16);
            float w3 = __uint_as_float(p23 & 0xffff0000u);
            float tr = thr[r];
            float rs;
            rs = __fmul_rn((b0 <= tr) ? eb.x : 0.0f, w0);
            rs = fmaf((b1 <= tr) ? eb.y : 0.0f, w1, rs);
            rs = fmaf((b2 <= tr) ? eb.z : 0.0f, w2, rs);
            rs = fmaf((b3 <= tr) ? eb.w : 0.0f, w3, rs);
            acc = fmaf(eaa[r], rs, acc);
        }

        u += cu; v += cv;

        if (k < k1 - 1) {
            if (!PRE) stage_write(st2, sl[(k & 1) ^ 1], tid);
            __syncthreads();                    // drains vmcnt -> next slice ready
        }
    }

    if (active) atomicAdd(out + lor, acc * pathL);
}

template <bool PRE>
__global__ __launch_bounds__(TPB, 8) void proj_fused(const float* __restrict__ img,
                                                     const ushort* __restrict__ V0,
                                                     const ushort* __restrict__ V1,
                                                     const ushort* __restrict__ V2,
                                                     const float* __restrict__ xl,
                                                     const float* __restrict__ yl,
                                                     const float* __restrict__ zl,
                                                     float* __restrict__ out,
                                                     int n, int nblk)
{
    __shared__ ushort sl[2][16384];   // double-buffered bf16 slice (64 KiB)
    __shared__ float4 wtab[QTAB];     // 16 KiB weight table
    int per = nblk * KSPLIT;
    int axis = blockIdx.x / per;
    int r = blockIdx.x - axis * per;
    int blk = r >> 2;                 // KSPLIT = 4
    int ks  = r & 3;
    if (axis == 0)      proj_axis<0, PRE>(sl, wtab, V0, img, xl, out, n, blk, ks);
    else if (axis == 1) proj_axis<1, PRE>(sl, wtab, V1, img, yl, out + n, n, blk, ks);
    else                proj_axis<2, PRE>(sl, wtab, V2, img, zl, out + 2 * (size_t)n, n, blk, ks);
}

extern "C" void kernel_launch(void* const* d_in, const int* in_sizes, int n_in,
                              void* d_out, int out_size, void* d_ws, size_t ws_size,
                              hipStream_t stream) {
    const float* img   = (const float*)d_in[0];
    const float* xlors = (const float*)d_in[1];
    const float* ylors = (const float*)d_in[2];
    const float* zlors = (const float*)d_in[3];
    float* out = (float*)d_out;

    int n = in_sizes[1] / 6;
    int nblk = (n + LPB - 1) / LPB;
    int m = 3 * n;

    zero_kernel<<<(m + 1023) / 1024, 1024, 0, stream>>>(out, m);

    constexpr size_t VOL = 128 * 128 * 128;
    bool pre = ws_size >= 3 * VOL * sizeof(ushort);
    int grid = 3 * nblk * KSPLIT;

    if (pre) {
        ushort* V0 = (ushort*)d_ws;
        ushort* V1 = V0 + VOL;
        ushort* V2 = V1 + VOL;
        prep_kernel<<<VOL / 256, 256, 0, stream>>>(img, V0, V1, V2);
        proj_fused<true><<<grid, TPB, 0, stream>>>(img, V0, V1, V2,
                                                   xlors, ylors, zlors, out, n, nblk);
    } else {
        proj_fused<false><<<grid, TPB, 0, stream>>>(img, nullptr, nullptr, nullptr,
                                                    xlors, ylors, zlors, out, n, nblk);
    }
}